// Round 21
// baseline (390.417 us; speedup 1.0000x reference)
//
#include <hip/hip_runtime.h>
#include <hip/hip_bf16.h>

typedef __attribute__((ext_vector_type(8))) short short8;
typedef __attribute__((ext_vector_type(8))) unsigned short u16x8;
typedef __attribute__((ext_vector_type(4))) float f32x4;
typedef __attribute__((ext_vector_type(16))) float f32x16;
typedef unsigned int u32;

#define S_TOK 8192
#define MDIM  1024
#define NEXP  8
#define HDIM  4096
#define CAP   2048   // TOP_K * ceil(S/E) * CF = 2*1024

__device__ __forceinline__ void gll16(const void* g, void* l) {
  __builtin_amdgcn_global_load_lds((const __attribute__((address_space(1))) u32*)g,
                                   (__attribute__((address_space(3))) u32*)l, 16, 0, 0);
}

// ---------------- prep: fused w1-transpose (blocks 0..8191) + gate (blocks 8192..10239) ----
__global__ __launch_bounds__(256) void prep_kernel(
    const float* __restrict__ x, const float* __restrict__ wg,
    const float* __restrict__ w1, __hip_bfloat16* __restrict__ w1t,
    __hip_bfloat16* __restrict__ xbf, float* __restrict__ me_part,
    int* __restrict__ topk, float* __restrict__ gnorm)
{
  __shared__ __align__(16) union {
    float tile[64][68];
    struct { float swg[NEXP * MDIM]; float gsh[4][8]; } g;
  } sh;
  const int b = blockIdx.x;
  const int tid = threadIdx.x;

  if (b < 8192) {
    // ---- transpose+cvt w1: [E][M][H] -> w1t [E][H][M] ----
    const int bx = b & 63;          // HDIM/64 col-blocks
    const int by = (b >> 6) & 15;   // MDIM/64 row-blocks
    const int bz = b >> 10;         // expert
    const float* ine = w1 + (size_t)bz * MDIM * HDIM;
    __hip_bfloat16* oute = w1t + (size_t)bz * MDIM * HDIM;
    const int cb = bx * 64;
    const int rb = by * 64;
    const int rr = tid >> 4;
    const int c4 = (tid & 15) * 4;
    #pragma unroll
    for (int i = 0; i < 4; ++i) {
      int r = rr + i * 16;
      float4 v = *(const float4*)&ine[(size_t)(rb + r) * HDIM + cb + c4];
      sh.tile[r][c4 + 0] = v.x; sh.tile[r][c4 + 1] = v.y;
      sh.tile[r][c4 + 2] = v.z; sh.tile[r][c4 + 3] = v.w;
    }
    __syncthreads();
    const int oc = tid >> 2;
    const int sg = (tid & 3) * 16;
    union { unsigned short u[16]; ushort4 v4[4]; } tu;
    #pragma unroll
    for (int j = 0; j < 16; ++j) {
      __hip_bfloat16 bb = __float2bfloat16(sh.tile[sg + j][oc]);
      tu.u[j] = *reinterpret_cast<const unsigned short*>(&bb);
    }
    ushort4* dst = (ushort4*)&oute[(size_t)(cb + oc) * MDIM + rb + sg];
    #pragma unroll
    for (int q = 0; q < 4; ++q) dst[q] = tu.v4[q];
    return;
  }

  // ---- gate: logits, softmax, top-2, bf16 x copy, partial me ----
  const int gb = b - 8192;
  #pragma unroll
  for (int i = 0; i < 8; ++i) {
    int idx = tid + i * 256;   // 2048 float4 = 8192 floats
    ((float4*)sh.g.swg)[idx] = ((const float4*)wg)[idx];
  }
  __syncthreads();
  const int w = tid >> 6, l = tid & 63;
  const int s = gb * 4 + w;
  const float* xr = x + (size_t)s * MDIM;
  __hip_bfloat16* xbr = xbf + (size_t)s * MDIM;
  float a[8] = {0,0,0,0,0,0,0,0};
  for (int j = 0; j < 16; ++j) {
    float xv = xr[l + j * 64];
    xbr[l + j * 64] = __float2bfloat16(xv);   // token-order bf16 copy (for GEMM1 gather)
    #pragma unroll
    for (int e = 0; e < 8; ++e) a[e] += xv * sh.g.swg[e * MDIM + l + j * 64];
  }
  #pragma unroll
  for (int e = 0; e < 8; ++e)
    #pragma unroll
    for (int off = 32; off > 0; off >>= 1)
      a[e] += __shfl_xor(a[e], off);
  if (l == 0) {
    float m = a[0]; int i1 = 0;
    #pragma unroll
    for (int e = 1; e < 8; ++e) if (a[e] > m) { m = a[e]; i1 = e; }
    float den = 0.f, g[8];
    #pragma unroll
    for (int e = 0; e < 8; ++e) { g[e] = __expf(a[e] - m); den += g[e]; }
    float inv = 1.f / den;
    float m2 = -3.4e38f; int i2 = 0;
    #pragma unroll
    for (int e = 0; e < 8; ++e) if (e != i1 && a[e] > m2) { m2 = a[e]; i2 = e; }
    #pragma unroll
    for (int e = 0; e < 8; ++e) sh.g.gsh[w][e] = g[e] * inv;
    float gs1 = inv;                    // exp(0)/den  (top-1 gate)
    float gs2 = __expf(m2 - m) * inv;   // top-2 gate
    float ssum = fmaxf(gs1 + gs2, 1.1920929e-7f);
    topk[s * 2 + 0] = i1; topk[s * 2 + 1] = i2;
    gnorm[s * 2 + 0] = gs1 / ssum; gnorm[s * 2 + 1] = gs2 / ssum;
  }
  __syncthreads();
  if (tid < 8)
    me_part[(size_t)gb * 8 + tid] =
        sh.g.gsh[0][tid] + sh.g.gsh[1][tid] + sh.g.gsh[2][tid] + sh.g.gsh[3][tid];
}

// ---------------- scan: token-order locations, capacity, slot map, l_loss ----------------
__global__ __launch_bounds__(1024) void scan_kernel(
    const int* __restrict__ topk, const float* __restrict__ gnorm,
    const float* __restrict__ me_part, __hip_bfloat16* __restrict__ xbf,
    int* __restrict__ gflat, float* __restrict__ gw,
    int* __restrict__ slot2tok, float* __restrict__ lloss)
{
  __shared__ union {
    float mef[8192];
    struct { u16x8 s0[1024]; u16x8 s1[1024]; } sc;
  } sh;
  __shared__ float me_s[8];
  __shared__ int tot_s[8];
  const int t = threadIdx.x;

  #pragma unroll
  for (int i = 0; i < 16; ++i) slot2tok[t + i * 1024] = -1;
  // zero row 8192 of xbf (gather target for empty slots)
  xbf[(size_t)8192 * MDIM + t] = __float2bfloat16(0.f);

  int e1[8], e2[8];
  #pragma unroll
  for (int i = 0; i < 8; ++i) {
    e1[i] = topk[(t * 8 + i) * 2 + 0];
    e2[i] = topk[(t * 8 + i) * 2 + 1];
  }

  // ---- me = sum of per-block partial sums (2048 x 8) ----
  {
    const float* mp = me_part + (size_t)t * 16;
    #pragma unroll
    for (int e = 0; e < 8; ++e) sh.mef[t * 8 + e] = mp[e] + mp[8 + e];
  }
  __syncthreads();
  for (int off = 512; off > 0; off >>= 1) {
    if (t < off) {
      #pragma unroll
      for (int e = 0; e < 8; ++e) sh.mef[t * 8 + e] += sh.mef[(t + off) * 8 + e];
    }
    __syncthreads();
  }
  if (t < 8) me_s[t] = sh.mef[t];
  __syncthreads();

  // ---- per-thread local counts (8 tokens, packed 4-bit) ----
  u32 p0 = 0, p1 = 0;
  #pragma unroll
  for (int i = 0; i < 8; ++i) { p0 += 1u << (4 * e1[i]); p1 += 1u << (4 * e2[i]); }
  union { unsigned short a[8]; u16x8 v; } c0u, c1u;
  #pragma unroll
  for (int e = 0; e < 8; ++e) {
    c0u.a[e] = (unsigned short)((p0 >> (4 * e)) & 15u);
    c1u.a[e] = (unsigned short)((p1 >> (4 * e)) & 15u);
  }
  sh.sc.s0[t] = c0u.v;
  sh.sc.s1[t] = c1u.v;
  __syncthreads();
  // inclusive Hillis-Steele scan over 1024 threads (8-wide vectors)
  for (int off = 1; off < 1024; off <<= 1) {
    u16x8 v0 = (u16x8)(unsigned short)0, v1 = v0;
    const bool p = (t >= off);
    if (p) { v0 = sh.sc.s0[t - off]; v1 = sh.sc.s1[t - off]; }
    __syncthreads();
    if (p) { sh.sc.s0[t] = sh.sc.s0[t] + v0; sh.sc.s1[t] = sh.sc.s1[t] + v1; }
    __syncthreads();
  }
  if (t == 0) {
    u16x8 tv = sh.sc.s0[1023];
    #pragma unroll
    for (int e = 0; e < 8; ++e) tot_s[e] = (int)tv[e];
  }
  __syncthreads();
  // exclusive (own row only; no cross-thread reads after this)
  sh.sc.s0[t] = sh.sc.s0[t] - c0u.v;
  sh.sc.s1[t] = sh.sc.s1[t] - c1u.v;

  const unsigned short* r0 = (const unsigned short*)&sh.sc.s0[t];
  const unsigned short* r1 = (const unsigned short*)&sh.sc.s1[t];
  #pragma unroll
  for (int i = 0; i < 8; ++i) {
    int s = t * 8 + i;
    int cnt0 = 0, cnt1 = 0;
    #pragma unroll
    for (int j = 0; j < 8; ++j) if (j < i) { cnt0 += (e1[j] == e1[i]); cnt1 += (e2[j] == e2[i]); }
    int loc0 = (int)r0[e1[i]] + cnt0;
    int loc1 = tot_s[e2[i]] + (int)r1[e2[i]] + cnt1;
    int v0 = loc0 < CAP, v1 = loc1 < CAP;
    int f0 = e1[i] * CAP + (loc0 < CAP ? loc0 : CAP - 1);
    int f1 = e2[i] * CAP + (loc1 < CAP ? loc1 : CAP - 1);
    gflat[s * 2 + 0] = f0; gflat[s * 2 + 1] = f1;
    float gn0 = gnorm[s * 2 + 0], gn1 = gnorm[s * 2 + 1];
    gw[s * 2 + 0] = v0 ? gn0 : 0.f;
    gw[s * 2 + 1] = v1 ? gn1 : 0.f;
    if (v0) slot2tok[f0] = s;
    if (v1) slot2tok[f1] = s;
  }
  if (t == 0) {
    float ll = 0.f;
    #pragma unroll
    for (int e = 0; e < 8; ++e) ll += me_s[e] * (float)tot_s[e];
    *lloss = ll * ((float)NEXP / ((float)S_TOK * (float)S_TOK));
  }
}

// ---------------- grouped GEMM, 256x256 tile, BK=64, 32x32x16 MFMA ----------------
// R6/R20 skeleton (stage-all-at-tile-start, 1 W0+BAR per tile, hoisted addressing,
// GATHER for GEMM1, XPOSE T14-split w2-transpose ride) with the MFMA shape swapped
// to mfma_f32_32x32x16_bf16: per-wave 128x64 = 4x2 frags of 32x32, K=64 = 4 ksteps.
// Same LDS layout + swizzle: slot(q,lane) = ((q<<1)|khi2) ^ rx = (q<<1)^(khi2^rx).
// A-frag: row = l&31, k = (l>>5)*8 + i (family pattern of the verified 16x16x32).
// C/D (HW-verified m74/m101): col = l&31, row = (reg&3) + 8*(reg>>2) + 4*(l>>5).
template<int RELU, int OUTBF16, int GATHER, int XPOSE>
__global__ __launch_bounds__(512, 2) void gemm256_kernel(
    const __hip_bfloat16* __restrict__ A, const __hip_bfloat16* __restrict__ Bt,
    const int* __restrict__ s2t,
    const float* __restrict__ bias, void* __restrict__ Cv,
    const float* __restrict__ xin, __hip_bfloat16* __restrict__ xout,
    int Mr, int N, int K, int TN, int tiles_per_e, int nwg)
{
  __shared__ __align__(16) char lds[131072 + (XPOSE ? 16640 : 0)];
  float* const tf = (float*)(lds + 131072);
  const int tid = threadIdx.x;
  const int bid = blockIdx.x;
  const int cpx = nwg >> 3;
  const int swz = (bid & 7) * cpx + (bid >> 3);
  const int e  = swz / tiles_per_e;
  const int rem = swz - e * tiles_per_e;
  const int tm = rem / TN;
  const int tn = rem - tm * TN;

  const int w  = tid >> 6, l = tid & 63;
  const int wr = w >> 2;          // 0..1  (M warps: 128 rows each)
  const int wc = w & 3;           // 0..3  (N warps: 64 cols each)
  const int l31 = l & 31;
  const int khi2 = l >> 5;        // 0..1
  const int rx = l & 7;           // swizzle key (row&7 == l&7 for all frags)
  const int wu = __builtin_amdgcn_readfirstlane(w);

  const __hip_bfloat16* Bbase = Bt + ((size_t)e * N + (size_t)tn * 256) * K;

  // ---- loop-invariant LDS read bases (precomputed swizzle) ----
  // slot byte offsets per kstep q: ((q<<1)^(khi2^rx))<<4 = oq
  const int o0 = ((khi2 ^ rx) << 4);
  const int o1 = o0 ^ 32;
  const int o2 = o0 ^ 64;
  const int o3 = o0 ^ 96;
  const char* const laA = lds + (wr * 128 + l31) * 128;           // + oq + mi*4096 + bo
  const char* const laB = lds + 32768 + (wc * 64 + l31) * 128;    // + oq + ni*4096 + bo

  // ---- loop-invariant stage pointers (advance += 64 bf16 per K-tile) ----
  const int srow = tid >> 3;                       // 0..63
  const int gs   = (tid & 7) ^ (srow & 7);         // inverse-swizzled source slot
  const __hip_bfloat16 *sA0, *sA0b, *sA1, *sA1b;
  if (GATHER) {
    const int sbase = e * CAP + tm * 256 + srow;   // GLOBAL slot space
    int t0 = s2t[sbase];       if (t0 < 0) t0 = S_TOK;
    int t1 = s2t[sbase + 64];  if (t1 < 0) t1 = S_TOK;
    int t2 = s2t[sbase + 128]; if (t2 < 0) t2 = S_TOK;
    int t3 = s2t[sbase + 192]; if (t3 < 0) t3 = S_TOK;
    sA0  = A + (size_t)t0 * K + gs * 8;
    sA0b = A + (size_t)t1 * K + gs * 8;
    sA1  = A + (size_t)t2 * K + gs * 8;
    sA1b = A + (size_t)t3 * K + gs * 8;
  } else {
    const __hip_bfloat16* Abase = A + ((size_t)e * Mr + (size_t)tm * 256) * K;
    sA0  = Abase + (size_t)srow * K + gs * 8;
    sA0b = sA0 + (size_t)64  * K;
    sA1  = sA0 + (size_t)128 * K;
    sA1b = sA0 + (size_t)192 * K;
  }
  const __hip_bfloat16* sB0  = Bbase + (size_t)srow * K + gs * 8;
  const __hip_bfloat16* sB0b = sB0 + (size_t)64  * K;
  const __hip_bfloat16* sB1  = sB0 + (size_t)128 * K;
  const __hip_bfloat16* sB1b = sB0 + (size_t)192 * K;
  char* const dstBase = lds + wu * 1024;           // wave-uniform LDS dest base

  // ---- transpose-ride lane constants (XPOSE) ----
  const int xr_ = tid >> 3;             // 0..63
  const int xc_ = (tid & 7) * 8;        // 8-col group
  float4 xa4, xb4;                      // in-flight f32 tile regs

  f32x16 acc[4][2];
  #pragma unroll
  for (int m = 0; m < 4; ++m)
    #pragma unroll
    for (int n = 0; n < 2; ++n)
      acc[m][n] = (f32x16)(0.f);

  short8 af[4];   // A frags for current kstep (4 mi)
  short8 bf2[2];  // B frags for current kstep (2 ni)

  #define STAGE8(nbo_)                                                   \
    do {                                                                 \
      char* d = dstBase + (nbo_);                                        \
      gll16(sA0,  d);          gll16(sA0b, d + 8192);                    \
      gll16(sB0,  d + 32768);  gll16(sB0b, d + 40960);                   \
      gll16(sB1,  d + 49152);  gll16(sB1b, d + 57344);                   \
      gll16(sA1,  d + 16384);  gll16(sA1b, d + 24576);                   \
      sA0 += 64; sA0b += 64; sA1 += 64; sA1b += 64;                      \
      sB0 += 64; sB0b += 64; sB1 += 64; sB1b += 64;                      \
    } while (0)

  auto qblock = [&](const char* pA, const char* pB) {
    #pragma unroll
    for (int mi = 0; mi < 4; ++mi) af[mi] = *(const short8*)(pA + mi * 4096);
    bf2[0] = *(const short8*)(pB);
    bf2[1] = *(const short8*)(pB + 4096);
    __builtin_amdgcn_s_setprio(1);
    #pragma unroll
    for (int mi = 0; mi < 4; ++mi)
      #pragma unroll
      for (int ni = 0; ni < 2; ++ni)
        acc[mi][ni] = __builtin_amdgcn_mfma_f32_32x32x16_bf16(
            af[mi], bf2[ni], acc[mi][ni], 0, 0, 0);
    __builtin_amdgcn_s_setprio(0);
  };
  auto xstore = [&](int ti) {   // store transposed tile ti from tf (bf16, one 16B store)
    const int cb = (ti & 15) * 64;
    const int rb = ((ti >> 4) & 63) * 64;
    const int ez = ti >> 10;
    union { unsigned short u[8]; short8 v; } tu;
    #pragma unroll
    for (int j = 0; j < 8; ++j) {
      __hip_bfloat16 b = __float2bfloat16(tf[(xc_ + j) * 65 + xr_]);
      tu.u[j] = *reinterpret_cast<const unsigned short*>(&b);
    }
    __hip_bfloat16* oute = xout + (size_t)ez * (HDIM * MDIM)
                                + (size_t)(cb + xr_) * HDIM + rb + xc_;
    *(short8*)oute = tu.v;
  };

  #define BAR() __builtin_amdgcn_s_barrier()
  #define WV()  asm volatile("s_waitcnt vmcnt(0)" ::: "memory")
  #define WVL() asm volatile("s_waitcnt vmcnt(0) lgkmcnt(0)" ::: "memory")

  // prologue: stage tile 0 into buf 0
  STAGE8(0);
  WV(); BAR();

  const int NT = K >> 6;
  for (int t = 0; t < NT; ++t) {
    const int bo  = (t & 1) << 16;
    const int nbo = bo ^ 65536;
    const bool st = (t + 1 < NT);
    if (st) STAGE8(nbo);
    // ---- w2-transpose ride, T14-split (GEMM1 only) ----
    if (XPOSE) {
      if ((t & 1) == 0) {
        if (t > 0) xstore(bid * 8 + (t >> 1) - 1);       // store previous tile
        const int ti = bid * 8 + (t >> 1);               // issue current tile loads
        const int cb = (ti & 15) * 64;
        const int rb = ((ti >> 4) & 63) * 64;
        const int ez = ti >> 10;
        const float* ine = xin + (size_t)ez * (HDIM * MDIM)
                               + (size_t)(rb + xr_) * MDIM + cb + xc_;
        xa4 = *(const float4*)ine;          // lands under this iter's body
        xb4 = *(const float4*)(ine + 4);
      } else {
        float* trow = tf + xr_ * 65 + xc_;  // loads drained by end-of-iter-(t-1) vmcnt(0)
        trow[0] = xa4.x; trow[1] = xa4.y; trow[2] = xa4.z; trow[3] = xa4.w;
        trow[4] = xb4.x; trow[5] = xb4.y; trow[6] = xb4.z; trow[7] = xb4.w;
      }
    }
    const char* pA = laA + bo; const char* pB = laB + bo;
    // ---- 4 ksteps of K=16: JIT reads (6 b128) + 8 MFMA(32x32) each ----
    qblock(pA + o0, pB + o0);
    qblock(pA + o1, pB + o1);
    qblock(pA + o2, pB + o2);
    qblock(pA + o3, pB + o3);
    if (st || XPOSE) {
      if (XPOSE && (t & 1)) WVL(); else WV();   // lgkm drain only where tf is published
      BAR();
    }
  }
  if (XPOSE) xstore(bid * 8 + 7);          // final tile (tf published by iter-15 WVL+BAR)
  #undef BAR
  #undef WV
  #undef WVL
  #undef STAGE8

  // ---- epilogue: bias (+ReLU) and store ----
  // C/D frag layout: col = l31, row = (reg&3) + 8*(reg>>2) + 4*khi2
  const float* be = bias + (size_t)e * N + (size_t)tn * 256;
  const size_t cbase = ((size_t)e * Mr + (size_t)tm * 256) * N + (size_t)tn * 256;
  __hip_bfloat16* C16 = (__hip_bfloat16*)Cv + cbase;
  float* C32 = (float*)Cv + cbase;
  #pragma unroll
  for (int ni = 0; ni < 2; ++ni) {
    const int colL = wc * 64 + ni * 32 + l31;
    const float bv = be[colL];
    #pragma unroll
    for (int mi = 0; mi < 4; ++mi) {
      #pragma unroll
      for (int g = 0; g < 4; ++g) {
        const int rowL0 = wr * 128 + mi * 32 + g * 8 + khi2 * 4;
        #pragma unroll
        for (int j = 0; j < 4; ++j) {
          float v = acc[mi][ni][g * 4 + j] + bv;
          if (RELU) v = fmaxf(v, 0.f);
          if (OUTBF16) C16[(size_t)(rowL0 + j) * N + colL] = __float2bfloat16(v);
          else         C32[(size_t)(rowL0 + j) * N + colL] = v;
        }
      }
    }
  }
}

// ---------------- combine: y[s] = sum_k gw * eo[flat]  (eo is bf16) ----------------
__global__ __launch_bounds__(256) void combine_kernel(
    const __hip_bfloat16* __restrict__ eo, const int* __restrict__ gflat,
    const float* __restrict__ gw, float* __restrict__ y)
{
  const int s = blockIdx.x;
  const int f0 = gflat[s * 2 + 0], f1 = gflat[s * 2 + 1];
  const float g0 = gw[s * 2 + 0], g1 = gw[s * 2 + 1];
  const int c = threadIdx.x * 4;
  ushort4 a4 = *(const ushort4*)&eo[(size_t)f0 * MDIM + c];
  ushort4 b4 = *(const ushort4*)&eo[(size_t)f1 * MDIM + c];
  const __hip_bfloat16* ap = (const __hip_bfloat16*)&a4;
  const __hip_bfloat16* bp = (const __hip_bfloat16*)&b4;
  float4 r;
  r.x = g0 * __bfloat162float(ap[0]) + g1 * __bfloat162float(bp[0]);
  r.y = g0 * __bfloat162float(ap[1]) + g1 * __bfloat162float(bp[1]);
  r.z = g0 * __bfloat162float(ap[2]) + g1 * __bfloat162float(bp[2]);
  r.w = g0 * __bfloat162float(ap[3]) + g1 * __bfloat162float(bp[3]);
  *(float4*)&y[(size_t)s * MDIM + c] = r;
}

extern "C" void kernel_launch(void* const* d_in, const int* in_sizes, int n_in,
                              void* d_out, int out_size, void* d_ws, size_t ws_size,
                              hipStream_t stream)
{
  (void)in_sizes; (void)n_in; (void)out_size; (void)ws_size;
  const float* x  = (const float*)d_in[0];
  const float* wg = (const float*)d_in[1];
  const float* w1 = (const float*)d_in[2];
  const float* b1 = (const float*)d_in[3];
  const float* w2 = (const float*)d_in[4];
  const float* b2 = (const float*)d_in[5];
  float* y = (float*)d_out;
  float* lloss = y + (size_t)S_TOK * MDIM;

  char* ws = (char*)d_ws;
  __hip_bfloat16* w1t = (__hip_bfloat16*)(ws);                   // 64 MB  [E][H][M]
  __hip_bfloat16* w2t = (__hip_bfloat16*)(ws + (64ull << 20));   // 64 MB  [E][M][H]
  __hip_bfloat16* xbf = (__hip_bfloat16*)(ws + (128ull << 20));  // ~17 MB [S_TOK+1][M] bf16
  __hip_bfloat16* hbuf = (__hip_bfloat16*)(ws + (160ull << 20)); // 128 MB [E][CAP][H]
  __hip_bfloat16* eo = (__hip_bfloat16*)(ws + (288ull << 20));   // 32 MB  [E*CAP][M] bf16
  char* small = ws + (352ull << 20);
  float* me_part = (float*)(small);                    // 64 KB [2048][8]
  int*   topk  = (int*)  (small + 65536);              // 64 KB
  float* gnorm = (float*)(small + 2 * 65536);          // 64 KB
  int*   gflat = (int*)  (small + 3 * 65536);          // 64 KB
  float* gwv   = (float*)(small + 4 * 65536);          // 64 KB
  int*   s2t   = (int*)  (small + 5 * 65536);          // 64 KB

  // fused w1-transpose (8192 blocks) + gate (2048 blocks)
  prep_kernel<<<10240, 256, 0, stream>>>(x, wg, w1, w1t, xbf, me_part, topk, gnorm);
  scan_kernel<<<1, 1024, 0, stream>>>(topk, gnorm, me_part, xbf, gflat, gwv, s2t, lloss);
  // GEMM1 (gathered A from xbf via s2t) + w2-transpose ride: 1024 wg
  gemm256_kernel<1, 1, 1, 1><<<1024, 512, 0, stream>>>(
      xbf, w1t, s2t, b1, (void*)hbuf, w2, w2t, CAP, HDIM, MDIM, 16, 128, 1024);
  // GEMM2: M=2048, N=1024, K=4096 -> 256 wg
  gemm256_kernel<0, 1, 0, 0><<<256, 512, 0, stream>>>(
      hbuf, w2t, nullptr, b2, (void*)eo, nullptr, nullptr, CAP, MDIM, HDIM, 4, 32, 256);
  combine_kernel<<<S_TOK, 256, 0, stream>>>(eo, gflat, gwv, y);
}

// Round 22
// 366.011 us; speedup vs baseline: 1.0667x; 1.0667x over previous
//
#include <hip/hip_runtime.h>
#include <hip/hip_bf16.h>

typedef __attribute__((ext_vector_type(8))) short short8;
typedef __attribute__((ext_vector_type(8))) unsigned short u16x8;
typedef __attribute__((ext_vector_type(4))) float f32x4;
typedef unsigned int u32;

#define S_TOK 8192
#define MDIM  1024
#define NEXP  8
#define HDIM  4096
#define CAP   2048   // TOP_K * ceil(S/E) * CF = 2*1024

__device__ __forceinline__ void gll16(const void* g, void* l) {
  __builtin_amdgcn_global_load_lds((const __attribute__((address_space(1))) u32*)g,
                                   (__attribute__((address_space(3))) u32*)l, 16, 0, 0);
}

// ---------------- prep: fused w1-transpose (blocks 0..8191) + gate (blocks 8192..10239) ----
__global__ __launch_bounds__(256) void prep_kernel(
    const float* __restrict__ x, const float* __restrict__ wg,
    const float* __restrict__ w1, __hip_bfloat16* __restrict__ w1t,
    __hip_bfloat16* __restrict__ xbf, float* __restrict__ me_part,
    int* __restrict__ topk, float* __restrict__ gnorm)
{
  __shared__ __align__(16) union {
    float tile[64][68];
    struct { float swg[NEXP * MDIM]; float gsh[4][8]; } g;
  } sh;
  const int b = blockIdx.x;
  const int tid = threadIdx.x;

  if (b < 8192) {
    // ---- transpose+cvt w1: [E][M][H] -> w1t [E][H][M] ----
    const int bx = b & 63;          // HDIM/64 col-blocks
    const int by = (b >> 6) & 15;   // MDIM/64 row-blocks
    const int bz = b >> 10;         // expert
    const float* ine = w1 + (size_t)bz * MDIM * HDIM;
    __hip_bfloat16* oute = w1t + (size_t)bz * MDIM * HDIM;
    const int cb = bx * 64;
    const int rb = by * 64;
    const int rr = tid >> 4;
    const int c4 = (tid & 15) * 4;
    #pragma unroll
    for (int i = 0; i < 4; ++i) {
      int r = rr + i * 16;
      float4 v = *(const float4*)&ine[(size_t)(rb + r) * HDIM + cb + c4];
      sh.tile[r][c4 + 0] = v.x; sh.tile[r][c4 + 1] = v.y;
      sh.tile[r][c4 + 2] = v.z; sh.tile[r][c4 + 3] = v.w;
    }
    __syncthreads();
    const int oc = tid >> 2;
    const int sg = (tid & 3) * 16;
    union { unsigned short u[16]; ushort4 v4[4]; } tu;
    #pragma unroll
    for (int j = 0; j < 16; ++j) {
      __hip_bfloat16 bb = __float2bfloat16(sh.tile[sg + j][oc]);
      tu.u[j] = *reinterpret_cast<const unsigned short*>(&bb);
    }
    ushort4* dst = (ushort4*)&oute[(size_t)(cb + oc) * MDIM + rb + sg];
    #pragma unroll
    for (int q = 0; q < 4; ++q) dst[q] = tu.v4[q];
    return;
  }

  // ---- gate: logits, softmax, top-2, bf16 x copy, partial me ----
  const int gb = b - 8192;
  #pragma unroll
  for (int i = 0; i < 8; ++i) {
    int idx = tid + i * 256;   // 2048 float4 = 8192 floats
    ((float4*)sh.g.swg)[idx] = ((const float4*)wg)[idx];
  }
  __syncthreads();
  const int w = tid >> 6, l = tid & 63;
  const int s = gb * 4 + w;
  const float* xr = x + (size_t)s * MDIM;
  __hip_bfloat16* xbr = xbf + (size_t)s * MDIM;
  float a[8] = {0,0,0,0,0,0,0,0};
  for (int j = 0; j < 16; ++j) {
    float xv = xr[l + j * 64];
    xbr[l + j * 64] = __float2bfloat16(xv);   // token-order bf16 copy (for GEMM1 gather)
    #pragma unroll
    for (int e = 0; e < 8; ++e) a[e] += xv * sh.g.swg[e * MDIM + l + j * 64];
  }
  #pragma unroll
  for (int e = 0; e < 8; ++e)
    #pragma unroll
    for (int off = 32; off > 0; off >>= 1)
      a[e] += __shfl_xor(a[e], off);
  if (l == 0) {
    float m = a[0]; int i1 = 0;
    #pragma unroll
    for (int e = 1; e < 8; ++e) if (a[e] > m) { m = a[e]; i1 = e; }
    float den = 0.f, g[8];
    #pragma unroll
    for (int e = 0; e < 8; ++e) { g[e] = __expf(a[e] - m); den += g[e]; }
    float inv = 1.f / den;
    float m2 = -3.4e38f; int i2 = 0;
    #pragma unroll
    for (int e = 0; e < 8; ++e) if (e != i1 && a[e] > m2) { m2 = a[e]; i2 = e; }
    #pragma unroll
    for (int e = 0; e < 8; ++e) sh.g.gsh[w][e] = g[e] * inv;
    float gs1 = inv;                    // exp(0)/den  (top-1 gate)
    float gs2 = __expf(m2 - m) * inv;   // top-2 gate
    float ssum = fmaxf(gs1 + gs2, 1.1920929e-7f);
    topk[s * 2 + 0] = i1; topk[s * 2 + 1] = i2;
    gnorm[s * 2 + 0] = gs1 / ssum; gnorm[s * 2 + 1] = gs2 / ssum;
  }
  __syncthreads();
  if (tid < 8)
    me_part[(size_t)gb * 8 + tid] =
        sh.g.gsh[0][tid] + sh.g.gsh[1][tid] + sh.g.gsh[2][tid] + sh.g.gsh[3][tid];
}

// ---------------- scan: token-order locations, capacity, slot map, l_loss ----------------
__global__ __launch_bounds__(1024) void scan_kernel(
    const int* __restrict__ topk, const float* __restrict__ gnorm,
    const float* __restrict__ me_part, __hip_bfloat16* __restrict__ xbf,
    int* __restrict__ gflat, float* __restrict__ gw,
    int* __restrict__ slot2tok, float* __restrict__ lloss)
{
  __shared__ union {
    float mef[8192];
    struct { u16x8 s0[1024]; u16x8 s1[1024]; } sc;
  } sh;
  __shared__ float me_s[8];
  __shared__ int tot_s[8];
  const int t = threadIdx.x;

  #pragma unroll
  for (int i = 0; i < 16; ++i) slot2tok[t + i * 1024] = -1;
  // zero row 8192 of xbf (gather target for empty slots)
  xbf[(size_t)8192 * MDIM + t] = __float2bfloat16(0.f);

  int e1[8], e2[8];
  #pragma unroll
  for (int i = 0; i < 8; ++i) {
    e1[i] = topk[(t * 8 + i) * 2 + 0];
    e2[i] = topk[(t * 8 + i) * 2 + 1];
  }

  // ---- me = sum of per-block partial sums (2048 x 8) ----
  {
    const float* mp = me_part + (size_t)t * 16;
    #pragma unroll
    for (int e = 0; e < 8; ++e) sh.mef[t * 8 + e] = mp[e] + mp[8 + e];
  }
  __syncthreads();
  for (int off = 512; off > 0; off >>= 1) {
    if (t < off) {
      #pragma unroll
      for (int e = 0; e < 8; ++e) sh.mef[t * 8 + e] += sh.mef[(t + off) * 8 + e];
    }
    __syncthreads();
  }
  if (t < 8) me_s[t] = sh.mef[t];
  __syncthreads();

  // ---- per-thread local counts (8 tokens, packed 4-bit) ----
  u32 p0 = 0, p1 = 0;
  #pragma unroll
  for (int i = 0; i < 8; ++i) { p0 += 1u << (4 * e1[i]); p1 += 1u << (4 * e2[i]); }
  union { unsigned short a[8]; u16x8 v; } c0u, c1u;
  #pragma unroll
  for (int e = 0; e < 8; ++e) {
    c0u.a[e] = (unsigned short)((p0 >> (4 * e)) & 15u);
    c1u.a[e] = (unsigned short)((p1 >> (4 * e)) & 15u);
  }
  sh.sc.s0[t] = c0u.v;
  sh.sc.s1[t] = c1u.v;
  __syncthreads();
  // inclusive Hillis-Steele scan over 1024 threads (8-wide vectors)
  for (int off = 1; off < 1024; off <<= 1) {
    u16x8 v0 = (u16x8)(unsigned short)0, v1 = v0;
    const bool p = (t >= off);
    if (p) { v0 = sh.sc.s0[t - off]; v1 = sh.sc.s1[t - off]; }
    __syncthreads();
    if (p) { sh.sc.s0[t] = sh.sc.s0[t] + v0; sh.sc.s1[t] = sh.sc.s1[t] + v1; }
    __syncthreads();
  }
  if (t == 0) {
    u16x8 tv = sh.sc.s0[1023];
    #pragma unroll
    for (int e = 0; e < 8; ++e) tot_s[e] = (int)tv[e];
  }
  __syncthreads();
  // exclusive (own row only; no cross-thread reads after this)
  sh.sc.s0[t] = sh.sc.s0[t] - c0u.v;
  sh.sc.s1[t] = sh.sc.s1[t] - c1u.v;

  const unsigned short* r0 = (const unsigned short*)&sh.sc.s0[t];
  const unsigned short* r1 = (const unsigned short*)&sh.sc.s1[t];
  #pragma unroll
  for (int i = 0; i < 8; ++i) {
    int s = t * 8 + i;
    int cnt0 = 0, cnt1 = 0;
    #pragma unroll
    for (int j = 0; j < 8; ++j) if (j < i) { cnt0 += (e1[j] == e1[i]); cnt1 += (e2[j] == e2[i]); }
    int loc0 = (int)r0[e1[i]] + cnt0;
    int loc1 = tot_s[e2[i]] + (int)r1[e2[i]] + cnt1;
    int v0 = loc0 < CAP, v1 = loc1 < CAP;
    int f0 = e1[i] * CAP + (loc0 < CAP ? loc0 : CAP - 1);
    int f1 = e2[i] * CAP + (loc1 < CAP ? loc1 : CAP - 1);
    gflat[s * 2 + 0] = f0; gflat[s * 2 + 1] = f1;
    float gn0 = gnorm[s * 2 + 0], gn1 = gnorm[s * 2 + 1];
    gw[s * 2 + 0] = v0 ? gn0 : 0.f;
    gw[s * 2 + 1] = v1 ? gn1 : 0.f;
    if (v0) slot2tok[f0] = s;
    if (v1) slot2tok[f1] = s;
  }
  if (t == 0) {
    float ll = 0.f;
    #pragma unroll
    for (int e = 0; e < 8; ++e) ll += me_s[e] * (float)tot_s[e];
    *lloss = ll * ((float)NEXP / ((float)S_TOK * (float)S_TOK));
  }
}

// ---------------- grouped GEMM, 256x256 tile, BK=64, 1-barrier-per-K-tile ----------------
// R6 structure. GATHER=1: A-rows from s2t (global slot space).
// XPOSE=1 (GEMM1): w2 f32->bf16 transpose rides in the K-loop, T14-split:
//   even t: store tile (t/2-1) from tf (one 16B global store); issue tile (t/2) loads
//   odd  t: write regs -> tf
// Sync: lgkmcnt(0) drain only at end of ODD iters (publishes tf); even iters vmcnt-only.
template<int RELU, int OUTBF16, int GATHER, int XPOSE>
__global__ __launch_bounds__(512, 2) void gemm256_kernel(
    const __hip_bfloat16* __restrict__ A, const __hip_bfloat16* __restrict__ Bt,
    const int* __restrict__ s2t,
    const float* __restrict__ bias, void* __restrict__ Cv,
    const float* __restrict__ xin, __hip_bfloat16* __restrict__ xout,
    int Mr, int N, int K, int TN, int tiles_per_e, int nwg)
{
  __shared__ __align__(16) char lds[131072 + (XPOSE ? 16640 : 0)];
  float* const tf = (float*)(lds + 131072);
  const int tid = threadIdx.x;
  const int bid = blockIdx.x;
  const int cpx = nwg >> 3;
  const int swz = (bid & 7) * cpx + (bid >> 3);
  const int e  = swz / tiles_per_e;
  const int rem = swz - e * tiles_per_e;
  const int tm = rem / TN;
  const int tn = rem - tm * TN;

  const int w  = tid >> 6, l = tid & 63;
  const int wr = w >> 2;          // 0..1  (M warps)
  const int wc = w & 3;           // 0..3  (N warps)
  const int l15 = l & 15, khi = l >> 4;
  const int rx = l15 & 7;         // read-side swizzle key
  const int wu = __builtin_amdgcn_readfirstlane(w);

  const __hip_bfloat16* Bbase = Bt + ((size_t)e * N + (size_t)tn * 256) * K;

  const int v0 = (khi ^ rx) << 4;            // kk=0 swizzled 16B slot
  const char* const laK0 = lds + (wr * 64 + l15) * 128 + v0;
  const char* const laK1 = lds + (wr * 64 + l15) * 128 + (v0 ^ 64);
  const char* const lbK0 = lds + 32768 + (wc * 32 + l15) * 128 + v0;
  const char* const lbK1 = lds + 32768 + (wc * 32 + l15) * 128 + (v0 ^ 64);

  const int srow = tid >> 3;                       // 0..63
  const int gs   = (tid & 7) ^ (srow & 7);         // inverse-swizzled source slot
  const __hip_bfloat16 *sA0, *sA0b, *sA1, *sA1b;
  if (GATHER) {
    const int sbase = e * CAP + tm * 256 + srow;   // GLOBAL slot space
    int t0 = s2t[sbase];       if (t0 < 0) t0 = S_TOK;
    int t1 = s2t[sbase + 64];  if (t1 < 0) t1 = S_TOK;
    int t2 = s2t[sbase + 128]; if (t2 < 0) t2 = S_TOK;
    int t3 = s2t[sbase + 192]; if (t3 < 0) t3 = S_TOK;
    sA0  = A + (size_t)t0 * K + gs * 8;
    sA0b = A + (size_t)t1 * K + gs * 8;
    sA1  = A + (size_t)t2 * K + gs * 8;
    sA1b = A + (size_t)t3 * K + gs * 8;
  } else {
    const __hip_bfloat16* Abase = A + ((size_t)e * Mr + (size_t)tm * 256) * K;
    sA0  = Abase + (size_t)srow * K + gs * 8;
    sA0b = sA0 + (size_t)64  * K;
    sA1  = sA0 + (size_t)128 * K;
    sA1b = sA0 + (size_t)192 * K;
  }
  const __hip_bfloat16* sB0  = Bbase + (size_t)srow * K + gs * 8;
  const __hip_bfloat16* sB0b = sB0 + (size_t)64  * K;
  const __hip_bfloat16* sB1  = sB0 + (size_t)128 * K;
  const __hip_bfloat16* sB1b = sB0 + (size_t)192 * K;
  char* const dstBase = lds + wu * 1024;           // wave-uniform LDS dest base

  // ---- transpose-ride lane constants (XPOSE) ----
  const int xr_ = tid >> 3;             // 0..63
  const int xc_ = (tid & 7) * 8;        // 8-col group
  float4 xa4, xb4;                      // in-flight f32 tile regs

  f32x4 acc[8][4];
  #pragma unroll
  for (int m = 0; m < 8; ++m)
    #pragma unroll
    for (int n = 0; n < 4; ++n)
      acc[m][n] = (f32x4){0.f, 0.f, 0.f, 0.f};

  short8 af[4][2];
  short8 bfr[4][2];

  #define STAGE8(nbo_)                                                   \
    do {                                                                 \
      char* d = dstBase + (nbo_);                                        \
      gll16(sA0,  d);          gll16(sA0b, d + 8192);                    \
      gll16(sB0,  d + 32768);  gll16(sB0b, d + 40960);                   \
      gll16(sB1,  d + 49152);  gll16(sB1b, d + 57344);                   \
      gll16(sA1,  d + 16384);  gll16(sA1b, d + 24576);                   \
      sA0 += 64; sA0b += 64; sA1 += 64; sA1b += 64;                      \
      sB0 += 64; sB0b += 64; sB1 += 64; sB1b += 64;                      \
    } while (0)

  auto loadA = [&](int qm, const char* aK0, const char* aK1) {
    #pragma unroll
    for (int mi = 0; mi < 4; ++mi) {
      af[mi][0] = *(const short8*)(aK0 + qm * 16384 + mi * 2048);
      af[mi][1] = *(const short8*)(aK1 + qm * 16384 + mi * 2048);
    }
  };
  auto loadB = [&](int qn, const char* bK0, const char* bK1) {
    #pragma unroll
    for (int ni = 0; ni < 2; ++ni) {
      bfr[qn * 2 + ni][0] = *(const short8*)(bK0 + qn * 16384 + ni * 2048);
      bfr[qn * 2 + ni][1] = *(const short8*)(bK1 + qn * 16384 + ni * 2048);
    }
  };
  auto mfma8 = [&](int qm, int qn) {
    #pragma unroll
    for (int mi = 0; mi < 4; ++mi)
      #pragma unroll
      for (int ni = 0; ni < 2; ++ni)
        #pragma unroll
        for (int kk = 0; kk < 2; ++kk)
          acc[qm * 4 + mi][qn * 2 + ni] = __builtin_amdgcn_mfma_f32_16x16x32_bf16(
              af[mi][kk], bfr[qn * 2 + ni][kk], acc[qm * 4 + mi][qn * 2 + ni], 0, 0, 0);
  };
  auto xstore = [&](int ti) {   // store transposed tile ti from tf (bf16, one 16B store)
    const int cb = (ti & 15) * 64;
    const int rb = ((ti >> 4) & 63) * 64;
    const int ez = ti >> 10;
    union { unsigned short u[8]; short8 v; } tu;
    #pragma unroll
    for (int j = 0; j < 8; ++j) {
      __hip_bfloat16 b = __float2bfloat16(tf[(xc_ + j) * 65 + xr_]);
      tu.u[j] = *reinterpret_cast<const unsigned short*>(&b);
    }
    __hip_bfloat16* oute = xout + (size_t)ez * (HDIM * MDIM)
                                + (size_t)(cb + xr_) * HDIM + rb + xc_;
    *(short8*)oute = tu.v;
  };

  #define BAR() __builtin_amdgcn_s_barrier()
  #define WV()  asm volatile("s_waitcnt vmcnt(0)" ::: "memory")
  #define WVL() asm volatile("s_waitcnt vmcnt(0) lgkmcnt(0)" ::: "memory")

  // prologue: stage tile 0 into buf 0
  STAGE8(0);
  WV(); BAR();

  const int NT = K >> 6;
  for (int t = 0; t < NT; ++t) {
    const int bo  = (t & 1) << 16;
    const int nbo = bo ^ 65536;
    const bool st = (t + 1 < NT);
    if (st) STAGE8(nbo);
    // ---- w2-transpose ride, T14-split (GEMM1 only) ----
    if (XPOSE) {
      if ((t & 1) == 0) {
        if (t > 0) xstore(bid * 8 + (t >> 1) - 1);       // store previous tile
        const int ti = bid * 8 + (t >> 1);               // issue current tile loads
        const int cb = (ti & 15) * 64;
        const int rb = ((ti >> 4) & 63) * 64;
        const int ez = ti >> 10;
        const float* ine = xin + (size_t)ez * (HDIM * MDIM)
                               + (size_t)(rb + xr_) * MDIM + cb + xc_;
        xa4 = *(const float4*)ine;          // lands under this iter's body
        xb4 = *(const float4*)(ine + 4);
      } else {
        float* trow = tf + xr_ * 65 + xc_;  // loads drained by end-of-iter-(t-1) vmcnt(0)
        trow[0] = xa4.x; trow[1] = xa4.y; trow[2] = xa4.z; trow[3] = xa4.w;
        trow[4] = xb4.x; trow[5] = xb4.y; trow[6] = xb4.z; trow[7] = xb4.w;
      }
    }
    const char* aK0 = laK0 + bo; const char* aK1 = laK1 + bo;
    const char* bK0 = lbK0 + bo; const char* bK1 = lbK1 + bo;
    // phase A: A0 x {B0,B1}
    loadA(0, aK0, aK1); loadB(0, bK0, bK1); loadB(1, bK0, bK1);   // 16 ds_read_b128
    __builtin_amdgcn_s_setprio(1); mfma8(0, 0); mfma8(0, 1); __builtin_amdgcn_s_setprio(0);
    // phase B: A1 x {B0,B1}
    loadA(1, aK0, aK1);                                           // 8 ds_read_b128
    __builtin_amdgcn_s_setprio(1); mfma8(1, 0); mfma8(1, 1); __builtin_amdgcn_s_setprio(0);
    if (st || XPOSE) {
      if (XPOSE && (t & 1)) WVL(); else WV();   // lgkm drain only where tf is published
      BAR();
    }
  }
  if (XPOSE) xstore(bid * 8 + 7);          // final tile (tf published by iter-15 WVL+BAR)
  #undef BAR
  #undef WV
  #undef WVL
  #undef STAGE8

  // ---- epilogue: bias (+ReLU) and store ----
  const float* be = bias + (size_t)e * N + (size_t)tn * 256;
  const size_t cbase = ((size_t)e * Mr + (size_t)tm * 256) * N + (size_t)tn * 256;
  __hip_bfloat16* C16 = (__hip_bfloat16*)Cv + cbase;
  float* C32 = (float*)Cv + cbase;
  #pragma unroll
  for (int n = 0; n < 4; ++n) {
    const int colL = (n >> 1) * 128 + wc * 32 + (n & 1) * 16 + l15;
    const float bv = be[colL];
    #pragma unroll
    for (int m = 0; m < 8; ++m) {
      const int rowL = (m >> 2) * 128 + wr * 64 + (m & 3) * 16 + khi * 4;
      #pragma unroll
      for (int j = 0; j < 4; ++j) {
        float v = acc[m][n][j] + bv;
        if (RELU) v = fmaxf(v, 0.f);
        if (OUTBF16) C16[(size_t)(rowL + j) * N + colL] = __float2bfloat16(v);
        else         C32[(size_t)(rowL + j) * N + colL] = v;
      }
    }
  }
}

// ---------------- combine: y[s] = sum_k gw * eo[flat]  (eo is bf16) ----------------
__global__ __launch_bounds__(256) void combine_kernel(
    const __hip_bfloat16* __restrict__ eo, const int* __restrict__ gflat,
    const float* __restrict__ gw, float* __restrict__ y)
{
  const int s = blockIdx.x;
  const int f0 = gflat[s * 2 + 0], f1 = gflat[s * 2 + 1];
  const float g0 = gw[s * 2 + 0], g1 = gw[s * 2 + 1];
  const int c = threadIdx.x * 4;
  ushort4 a4 = *(const ushort4*)&eo[(size_t)f0 * MDIM + c];
  ushort4 b4 = *(const ushort4*)&eo[(size_t)f1 * MDIM + c];
  const __hip_bfloat16* ap = (const __hip_bfloat16*)&a4;
  const __hip_bfloat16* bp = (const __hip_bfloat16*)&b4;
  float4 r;
  r.x = g0 * __bfloat162float(ap[0]) + g1 * __bfloat162float(bp[0]);
  r.y = g0 * __bfloat162float(ap[1]) + g1 * __bfloat162float(bp[1]);
  r.z = g0 * __bfloat162float(ap[2]) + g1 * __bfloat162float(bp[2]);
  r.w = g0 * __bfloat162float(ap[3]) + g1 * __bfloat162float(bp[3]);
  *(float4*)&y[(size_t)s * MDIM + c] = r;
}

extern "C" void kernel_launch(void* const* d_in, const int* in_sizes, int n_in,
                              void* d_out, int out_size, void* d_ws, size_t ws_size,
                              hipStream_t stream)
{
  (void)in_sizes; (void)n_in; (void)out_size; (void)ws_size;
  const float* x  = (const float*)d_in[0];
  const float* wg = (const float*)d_in[1];
  const float* w1 = (const float*)d_in[2];
  const float* b1 = (const float*)d_in[3];
  const float* w2 = (const float*)d_in[4];
  const float* b2 = (const float*)d_in[5];
  float* y = (float*)d_out;
  float* lloss = y + (size_t)S_TOK * MDIM;

  char* ws = (char*)d_ws;
  __hip_bfloat16* w1t = (__hip_bfloat16*)(ws);                   // 64 MB  [E][H][M]
  __hip_bfloat16* w2t = (__hip_bfloat16*)(ws + (64ull << 20));   // 64 MB  [E][M][H]
  __hip_bfloat16* xbf = (__hip_bfloat16*)(ws + (128ull << 20));  // ~17 MB [S_TOK+1][M] bf16
  __hip_bfloat16* hbuf = (__hip_bfloat16*)(ws + (160ull << 20)); // 128 MB [E][CAP][H]
  __hip_bfloat16* eo = (__hip_bfloat16*)(ws + (288ull << 20));   // 32 MB  [E*CAP][M] bf16
  char* small = ws + (352ull << 20);
  float* me_part = (float*)(small);                    // 64 KB [2048][8]
  int*   topk  = (int*)  (small + 65536);              // 64 KB
  float* gnorm = (float*)(small + 2 * 65536);          // 64 KB
  int*   gflat = (int*)  (small + 3 * 65536);          // 64 KB
  float* gwv   = (float*)(small + 4 * 65536);          // 64 KB
  int*   s2t   = (int*)  (small + 5 * 65536);          // 64 KB

  // fused w1-transpose (8192 blocks) + gate (2048 blocks)
  prep_kernel<<<10240, 256, 0, stream>>>(x, wg, w1, w1t, xbf, me_part, topk, gnorm);
  scan_kernel<<<1, 1024, 0, stream>>>(topk, gnorm, me_part, xbf, gflat, gwv, s2t, lloss);
  // GEMM1 (gathered A from xbf via s2t) + w2-transpose ride: 1024 wg
  gemm256_kernel<1, 1, 1, 1><<<1024, 512, 0, stream>>>(
      xbf, w1t, s2t, b1, (void*)hbuf, w2, w2t, CAP, HDIM, MDIM, 16, 128, 1024);
  // GEMM2: M=2048, N=1024, K=4096 -> 256 wg
  gemm256_kernel<0, 1, 0, 0><<<256, 512, 0, stream>>>(
      hbuf, w2t, nullptr, b2, (void*)eo, nullptr, nullptr, CAP, MDIM, HDIM, 4, 32, 256);
  combine_kernel<<<S_TOK, 256, 0, stream>>>(eo, gflat, gwv, y);
}